// Round 8
// baseline (137.831 us; speedup 1.0000x reference)
//
#include <hip/hip_runtime.h>
#include <hip/hip_cooperative_groups.h>
#include <math.h>

namespace cg = cooperative_groups;

#define R 2048
#define C 1024
#define CH 8
#define K 64  // CH*BA

// Output layout (floats), reference return order:
#define OFF_P     0
#define OFF_TOT   (R*K)            // 131072
#define OFF_MAX   (OFF_TOT + 8)
#define OFF_NCOL  (OFF_MAX + 8)
#define OFF_NROW  (OFF_NCOL + 8)
#define OFF_NNZ   (OFF_NROW + 8)
#define OFF_DEN   (OFF_NNZ + 64)
#define OFF_SEL   (OFF_DEN + 8)

// ws layout (floats):
#define WS_LQ   0          // lq2[R][8]: clamped log2 of per-(row,ch) prod(1-p)
#define WS_COL  16384      // colacc[8][1024]: zeroed in phase A, atomics in B
#define WS_NP   24576      // nnzpart[256][64]
#define WS_NR   40960      // nrpart[256][8]
#define WS_SEL  43008      // selpart[256]

// One cooperative kernel, 256 blocks x 512 threads, two grid.sync()s.
__global__ __launch_bounds__(512) void fused(
    const float* __restrict__ W, const float* __restrict__ Dm,
    const float* __restrict__ g, float* __restrict__ ws,
    float* __restrict__ out)
{
    cg::grid_group grid = cg::this_grid();
    const int tid  = threadIdx.x;
    const int lane = tid & 63;
    const int w    = tid >> 6;           // wave 0..7
    const int b    = blockIdx.x;

    __shared__ float rn[8][64];          // phase A
    __shared__ float rp[8][8];
    __shared__ float rsel[8];
    __shared__ float part[2][256][8];    // phase B (16 KB)
    __shared__ float red[512];           // phase C
    __shared__ float npr[8][64];
    __shared__ float nrr[8][8];
    __shared__ float selr[64];
    __shared__ float nc8[8];

    // ================= phase A: per-row (former k1) =================
    {
        const int row = b * 8 + w;
        if (tid < 32) ws[WS_COL + b * 32 + tid] = 0.0f;

        float z = W[row * K + lane] + g[row * K + lane];
        float m = z;
        #pragma unroll
        for (int off = 32; off >= 1; off >>= 1)
            m = fmaxf(m, __shfl_xor(m, off, 64));
        float e = __expf(z - m);
        float s = e;
        #pragma unroll
        for (int off = 32; off >= 1; off >>= 1)
            s += __shfl_xor(s, off, 64);
        float p = e * __builtin_amdgcn_rcpf(s);
        out[OFF_P + row * K + lane] = p;

        const float4* Drow = (const float4*)(Dm + (size_t)row * C);
        float ds = 0.0f;
        #pragma unroll
        for (int j = 0; j < 4; ++j) {
            float4 v = Drow[lane + 64 * j];
            ds += (v.x + v.y) + (v.z + v.w);
        }
        #pragma unroll
        for (int off = 32; off >= 1; off >>= 1)
            ds += __shfl_xor(ds, off, 64);

        float om = 1.0f - p, sc = p;
        #pragma unroll
        for (int off = 1; off <= 4; off <<= 1) {
            om *= __shfl_xor(om, off, 64);
            sc += __shfl_xor(sc, off, 64);
        }
        if ((lane & 7) == 0)   // clamp: avoid -inf -> 0*-inf NaN in phase B
            ws[WS_LQ + row * CH + (lane >> 3)] =
                fmaxf(__builtin_amdgcn_logf(om), -1.0e30f);

        float pm = p;
        #pragma unroll
        for (int off = 32; off >= 1; off >>= 1)
            pm = fmaxf(pm, __shfl_xor(pm, off, 64));

        rn[w][lane] = p * ds;
        if ((lane & 7) == 0) rp[w][lane >> 3] = sc;
        if (lane == 0) rsel[w] = (pm > 0.99f) ? 1.0f : 0.0f;
        __syncthreads();

        if (tid < 64) {
            float v = rn[0][tid] + rn[1][tid] + rn[2][tid] + rn[3][tid]
                    + rn[4][tid] + rn[5][tid] + rn[6][tid] + rn[7][tid];
            ws[WS_NP + b * 64 + tid] = v;
        }
        if (tid < 8) {
            float v = 0.0f;
            #pragma unroll
            for (int ww = 0; ww < 8; ++ww) v += rp[ww][tid];
            ws[WS_NR + b * 8 + tid] = v;
        }
        if (tid == 0) {
            float v = 0.0f;
            #pragma unroll
            for (int ww = 0; ww < 8; ++ww) v += rsel[ww];
            ws[WS_SEL + b] = v;
        }
    }
    grid.sync();

    // ================= phase B: column log-sums (former k2) =================
    {
        const int ct  = b & 3;               // col tile (256 cols)
        const int rc  = b >> 2;              // row chunk (32 rows)
        const int s   = tid >> 8;            // subrow half (16 rows each)
        const int c   = tid & 255;
        const int col = ct * 256 + c;

        float l0=0,l1=0,l2=0,l3=0,l4=0,l5=0,l6=0,l7=0;
        const int r0 = rc * 32 + s * 16;
        #pragma unroll 4
        for (int i = 0; i < 16; ++i) {
            const int r = r0 + i;
            float d = Dm[(size_t)r * C + col];
            float4 qa = *(const float4*)(ws + WS_LQ + r * CH);
            float4 qb = *(const float4*)(ws + WS_LQ + r * CH + 4);
            l0 += d * qa.x; l1 += d * qa.y; l2 += d * qa.z; l3 += d * qa.w;
            l4 += d * qb.x; l5 += d * qb.y; l6 += d * qb.z; l7 += d * qb.w;
        }
        part[s][c][0] = l0; part[s][c][1] = l1;
        part[s][c][2] = l2; part[s][c][3] = l3;
        part[s][c][4] = l4; part[s][c][5] = l5;
        part[s][c][6] = l6; part[s][c][7] = l7;
        __syncthreads();

        #pragma unroll
        for (int ps = 0; ps < 4; ++ps) {
            const int flat = ps * 512 + tid;       // 2048 = 256 cols x 8 ch
            const int cc = flat >> 3, ch = flat & 7;
            float v = part[0][cc][ch] + part[1][cc][ch];
            atomicAdd(&ws[WS_COL + ch * 1024 + ct * 256 + cc], v);
        }
    }
    grid.sync();

    // ================= phase C: finalize on block 0 (former k3) =============
    if (b != 0) return;
    {
        {   // num_col: 1 - 2^colacc, per-ch partials (plain loads post-sync)
            const int ch = tid >> 6, c0 = tid & 63;
            float ncl = 0.0f;
            #pragma unroll
            for (int j = 0; j < 16; ++j)
                ncl += 1.0f - __builtin_amdgcn_exp2f(
                                  ws[WS_COL + ch * 1024 + j * 64 + c0]);
            red[tid] = ncl;
        }
        {   // nnz partials: 8 groups x 32 blocks
            const int l = tid & 63, grp = tid >> 6;
            float v = 0.0f;
            #pragma unroll
            for (int bb = 0; bb < 32; ++bb)
                v += ws[WS_NP + (grp * 32 + bb) * 64 + l];
            npr[grp][l] = v;
        }
        if (tid < 64) {
            const int ch = tid & 7, g2 = tid >> 3;
            float v = 0.0f;
            #pragma unroll
            for (int bb = 0; bb < 32; ++bb)
                v += ws[WS_NR + (g2 * 32 + bb) * CH + ch];
            nrr[g2][ch] = v;
            float sv = 0.0f;
            #pragma unroll
            for (int j = 0; j < 4; ++j)
                sv += ws[WS_SEL + j * 64 + tid];
            selr[tid] = sv;
        }
        __syncthreads();

        // reduce num_col within each per-ch 64-thread group
        #pragma unroll
        for (int off = 32; off >= 1; off >>= 1) {
            if ((tid & 63) < off) red[tid] += red[tid + off];
            __syncthreads();
        }
        if ((tid & 63) == 0) nc8[tid >> 6] = red[tid];
        __syncthreads();

        if (tid < 64) {
            float nnzv = npr[0][tid] + npr[1][tid] + npr[2][tid] + npr[3][tid]
                       + npr[4][tid] + npr[5][tid] + npr[6][tid] + npr[7][tid];
            out[OFF_NNZ + tid] = nnzv;

            float sum = nnzv, mx = nnzv;
            #pragma unroll
            for (int off = 1; off <= 4; off <<= 1) {
                sum += __shfl_xor(sum, off, 64);
                mx = fmaxf(mx, __shfl_xor(mx, off, 64));
            }
            float sv = selr[tid];
            #pragma unroll
            for (int off = 32; off >= 1; off >>= 1)
                sv += __shfl_xor(sv, off, 64);
            if (tid == 0) out[OFF_SEL] = sv;

            if ((tid & 7) == 0) {
                const int ch = tid >> 3;
                float nr = 0.0f;
                #pragma unroll
                for (int g2 = 0; g2 < 8; ++g2) nr += nrr[g2][ch];
                const float nc = nc8[ch];
                out[OFF_TOT  + ch] = mx + nc + nr;
                out[OFF_MAX  + ch] = mx;
                out[OFF_NCOL + ch] = nc;
                out[OFF_NROW + ch] = nr;
                out[OFF_DEN  + ch] = sum / nr / nc;
            }
        }
    }
}

extern "C" void kernel_launch(void* const* d_in, const int* in_sizes, int n_in,
                              void* d_out, int out_size, void* d_ws, size_t ws_size,
                              hipStream_t stream) {
    const float* W = (const float*)d_in[0];
    const float* D = (const float*)d_in[1];
    const float* g = (const float*)d_in[2];
    float* out = (float*)d_out;
    float* ws  = (float*)d_ws;

    void* args[] = { (void*)&W, (void*)&D, (void*)&g, (void*)&ws, (void*)&out };
    hipLaunchCooperativeKernel((void*)fused, dim3(256), dim3(512),
                               args, 0, stream);
}

// Round 9
// 79.584 us; speedup vs baseline: 1.7319x; 1.7319x over previous
//
#include <hip/hip_runtime.h>
#include <math.h>

#define R 2048
#define C 1024
#define CH 8
#define K 64  // CH*BA

// Output layout (floats), reference return order:
#define OFF_P     0
#define OFF_TOT   (R*K)            // 131072
#define OFF_MAX   (OFF_TOT + 8)
#define OFF_NCOL  (OFF_MAX + 8)
#define OFF_NROW  (OFF_NCOL + 8)
#define OFF_NNZ   (OFF_NROW + 8)
#define OFF_DEN   (OFF_NNZ + 64)
#define OFF_SEL   (OFF_DEN + 8)

// ws layout (word offsets):
#define WS_LQ   0          // lq2[R][8]: clamped log2 of per-(row,ch) prod(1-p)
#define WS_COL  16384      // colacc[8][1024]: zeroed by k1, atomics from k2
#define WS_NP   24576      // nnzpart[256][64]
#define WS_NR   40960      // nrpart[256][8]
#define WS_SEL  43008      // selpart[256]
#define WS_CNT  43264      // u32 ticket counter (zeroed by k1)

// ---------------------------------------------------------------- kernel 1
// One row per wave (2048 waves). Softmax -> P, lq2, D rowsum -> nnz partial.
// Also zeroes colacc + ticket counter (k2 starts only after k1 retires).
__global__ __launch_bounds__(512) void k1(
    const float* __restrict__ W, const float* __restrict__ Dm,
    const float* __restrict__ g, float* __restrict__ P,
    float* __restrict__ ws)
{
    const int tid  = threadIdx.x;
    const int lane = tid & 63;
    const int w    = tid >> 6;              // wave 0..7
    const int row  = blockIdx.x * 8 + w;

    if (tid < 32) ws[WS_COL + blockIdx.x * 32 + tid] = 0.0f;
    if (blockIdx.x == 0 && tid == 384) ((unsigned int*)ws)[WS_CNT] = 0u;

    // softmax over the row's 64 logits
    float z = W[row * K + lane] + g[row * K + lane];
    float m = z;
    #pragma unroll
    for (int off = 32; off >= 1; off >>= 1)
        m = fmaxf(m, __shfl_xor(m, off, 64));
    float e = __expf(z - m);
    float s = e;
    #pragma unroll
    for (int off = 32; off >= 1; off >>= 1)
        s += __shfl_xor(s, off, 64);
    float p = e * __builtin_amdgcn_rcpf(s);
    P[row * K + lane] = p;

    // D rowsum (coalesced float4, whole wave on one 4KB row)
    const float4* Drow = (const float4*)(Dm + (size_t)row * C);
    float ds = 0.0f;
    #pragma unroll
    for (int j = 0; j < 4; ++j) {
        float4 v = Drow[lane + 64 * j];
        ds += (v.x + v.y) + (v.z + v.w);
    }
    #pragma unroll
    for (int off = 32; off >= 1; off >>= 1)
        ds += __shfl_xor(ds, off, 64);

    // per-channel (8-lane group) product of (1-p), sum of p
    float om = 1.0f - p, sc = p;
    #pragma unroll
    for (int off = 1; off <= 4; off <<= 1) {
        om *= __shfl_xor(om, off, 64);
        sc += __shfl_xor(sc, off, 64);
    }
    if ((lane & 7) == 0)   // clamp: q==0 would give -inf, then 0*-inf = NaN in k2
        ws[WS_LQ + row * CH + (lane >> 3)] =
            fmaxf(__builtin_amdgcn_logf(om), -1.0e30f);

    // row max for num_row_sel
    float pm = p;
    #pragma unroll
    for (int off = 32; off >= 1; off >>= 1)
        pm = fmaxf(pm, __shfl_xor(pm, off, 64));

    // block-level combine (plain stores, no atomics)
    __shared__ float rn[8][64];
    __shared__ float rp[8][8];
    __shared__ float rsel[8];
    rn[w][lane] = p * ds;
    if ((lane & 7) == 0) rp[w][lane >> 3] = sc;
    if (lane == 0) rsel[w] = (pm > 0.99f) ? 1.0f : 0.0f;
    __syncthreads();

    if (tid < 64) {
        float v = rn[0][tid] + rn[1][tid] + rn[2][tid] + rn[3][tid]
                + rn[4][tid] + rn[5][tid] + rn[6][tid] + rn[7][tid];
        ws[WS_NP + blockIdx.x * 64 + tid] = v;
    }
    if (tid < 8) {
        float v = 0.0f;
        #pragma unroll
        for (int ww = 0; ww < 8; ++ww) v += rp[ww][tid];
        ws[WS_NR + blockIdx.x * 8 + tid] = v;
    }
    if (tid == 0) {
        float v = 0.0f;
        #pragma unroll
        for (int ww = 0; ww < 8; ++ww) v += rsel[ww];
        ws[WS_SEL + blockIdx.x] = v;
    }
}

// ---------------------------------------------------------------- kernel 2
// Round-5 k2 verbatim (256 blocks = 4 col-tiles x 64 row-chunks of 32 rows),
// plus a last-block-done finalize. Release ordering for the ticket is a bare
// s_waitcnt vmcnt(0) (atomics are already device-coherent once retired) --
// NO __threadfence, so no buffer_wbl2 L2-writeback storm (round-6's killer).
__global__ __launch_bounds__(256) void k2(
    const float* __restrict__ Dm, float* __restrict__ ws,
    float* __restrict__ out)
{
    const int tid = threadIdx.x;
    const int ct  = blockIdx.x & 3;
    const int rc  = blockIdx.x >> 2;
    const int col = ct * 256 + tid;

    float l0=0,l1=0,l2=0,l3=0,l4=0,l5=0,l6=0,l7=0;
    const int r0 = rc * 32;
    #pragma unroll 4
    for (int i = 0; i < 32; ++i) {
        const int r = r0 + i;
        float d = Dm[(size_t)r * C + col];
        const float* lr = ws + WS_LQ + r * CH;   // wave-uniform address
        l0 += d * lr[0]; l1 += d * lr[1]; l2 += d * lr[2]; l3 += d * lr[3];
        l4 += d * lr[4]; l5 += d * lr[5]; l6 += d * lr[6]; l7 += d * lr[7];
    }
    float* ca = ws + WS_COL;
    atomicAdd(&ca[0 * 1024 + col], l0);
    atomicAdd(&ca[1 * 1024 + col], l1);
    atomicAdd(&ca[2 * 1024 + col], l2);
    atomicAdd(&ca[3 * 1024 + col], l3);
    atomicAdd(&ca[4 * 1024 + col], l4);
    atomicAdd(&ca[5 * 1024 + col], l5);
    atomicAdd(&ca[6 * 1024 + col], l6);
    atomicAdd(&ca[7 * 1024 + col], l7);

    // ---- ticket: wait only for MY atomics (already coherent when retired)
    asm volatile("s_waitcnt vmcnt(0)" ::: "memory");
    __syncthreads();
    __shared__ int is_last;
    if (tid == 0) {
        unsigned int old = atomicAdd(&((unsigned int*)ws)[WS_CNT], 1u);
        is_last = (old == 255u) ? 1 : 0;
    }
    __syncthreads();
    if (!is_last) return;

    // =================== finalize (former k3), 256 threads ================
    __shared__ float red[256];
    __shared__ float npr[4][64];
    __shared__ float nrr[8][8];
    __shared__ float nc8[8];

    {   // num_col: pipelined agent-scope atomic LOADS (no RMW serialization)
        const int ch = tid >> 5, c0 = tid & 31;
        float ncl = 0.0f;
        #pragma unroll
        for (int j = 0; j < 32; ++j) {
            float v = __hip_atomic_load(&ws[WS_COL + ch * 1024 + j * 32 + c0],
                                        __ATOMIC_RELAXED,
                                        __HIP_MEMORY_SCOPE_AGENT);
            ncl += 1.0f - __builtin_amdgcn_exp2f(v);
        }
        red[tid] = ncl;
    }
    {   // nnz partials: 4 groups x 64 blocks (plain loads, k1-written)
        const int l = tid & 63, grp = tid >> 6;
        float v = 0.0f;
        #pragma unroll
        for (int bb = 0; bb < 64; ++bb)
            v += ws[WS_NP + (grp * 64 + bb) * 64 + l];
        npr[grp][l] = v;
    }
    if (tid < 64) {   // num_row partials: 8 groups x 32 blocks
        const int ch = tid & 7, g2 = tid >> 3;
        float v = 0.0f;
        #pragma unroll
        for (int bb = 0; bb < 32; ++bb)
            v += ws[WS_NR + (g2 * 32 + bb) * CH + ch];
        nrr[g2][ch] = v;
    }
    __syncthreads();

    // reduce num_col within each per-ch 32-thread group
    #pragma unroll
    for (int off = 16; off >= 1; off >>= 1) {
        if ((tid & 31) < off) red[tid] += red[tid + off];
        __syncthreads();
    }
    if ((tid & 31) == 0) nc8[tid >> 5] = red[tid];
    __syncthreads();

    if (tid < 64) {
        float nnzv = npr[0][tid] + npr[1][tid] + npr[2][tid] + npr[3][tid];
        out[OFF_NNZ + tid] = nnzv;

        float sum = nnzv, mx = nnzv;
        #pragma unroll
        for (int off = 1; off <= 4; off <<= 1) {
            sum += __shfl_xor(sum, off, 64);
            mx = fmaxf(mx, __shfl_xor(mx, off, 64));
        }

        float sv = ws[WS_SEL + tid] + ws[WS_SEL + 64 + tid]
                 + ws[WS_SEL + 128 + tid] + ws[WS_SEL + 192 + tid];
        #pragma unroll
        for (int off = 32; off >= 1; off >>= 1)
            sv += __shfl_xor(sv, off, 64);
        if (tid == 0) out[OFF_SEL] = sv;

        if ((tid & 7) == 0) {
            const int ch = tid >> 3;
            float nr = 0.0f;
            #pragma unroll
            for (int g2 = 0; g2 < 8; ++g2) nr += nrr[g2][ch];
            const float nc = nc8[ch];
            out[OFF_TOT  + ch] = mx + nc + nr;
            out[OFF_MAX  + ch] = mx;
            out[OFF_NCOL + ch] = nc;
            out[OFF_NROW + ch] = nr;
            out[OFF_DEN  + ch] = sum / nr / nc;
        }
    }
}

extern "C" void kernel_launch(void* const* d_in, const int* in_sizes, int n_in,
                              void* d_out, int out_size, void* d_ws, size_t ws_size,
                              hipStream_t stream) {
    const float* W = (const float*)d_in[0];
    const float* D = (const float*)d_in[1];
    const float* g = (const float*)d_in[2];
    float* out = (float*)d_out;
    float* ws  = (float*)d_ws;

    k1<<<256, 512, 0, stream>>>(W, D, g, out, ws);
    k2<<<256, 256, 0, stream>>>(D, ws, out);
}